// Round 4
// baseline (7582.198 us; speedup 1.0000x reference)
//
#include <hip/hip_runtime.h>

// Problem constants (from setup_inputs: B=16, N=16384, D=128, S=N/4)
#define BATCH    16
#define NPTS     16384
#define NSAMP    4096
#define NTHREADS 1024
#define PPT      16      // NPTS / NTHREADS, points per thread (contiguous)

// DPP helper: move with self-preserving old (disabled lanes keep own value)
template<int CTRL, int RM>
__device__ __forceinline__ unsigned dpp_mov(unsigned v) {
    return (unsigned)__builtin_amdgcn_update_dpp((int)v, (int)v, CTRL, RM, 0xF, false);
}

// One step of a (hi,lo) u64-key max reduction via DPP.
// hi = dist bits (non-negative fp32 -> uint order == float order)
// lo = ~global_index (max key => min index on dist ties)
template<int CTRL, int RM>
__device__ __forceinline__ void red_step(unsigned& hi, unsigned& lo) {
    unsigned h2 = dpp_mov<CTRL, RM>(hi);
    unsigned l2 = dpp_mov<CTRL, RM>(lo);
    bool take = (h2 > hi) || (h2 == hi && l2 > lo);
    hi = take ? h2 : hi;
    lo = take ? l2 : lo;
}

// -----------------------------------------------------------------------------
// FPS kernel: one block per batch, 1024 threads, 16 points/thread.
// Coordinates are PINNED into VGPRs via an opaque asm (otherwise the compiler
// rematerializes them from global every iteration). At PPT=16 the full state
// (~95 VGPR) fits 4 waves/SIMD with no AGPR/scratch spill (PPT=32 spilled:
// round-3 counter VGPR_Count=72 for 128 declared floats).
// Exact reference semantics: dist = min(dist, (x-cx)^2+(y-cy)^2+(z-cz)^2)
// (fp32, no FMA, (xx+yy)+zz association), argmax with first-index tie-break.
// Per iteration: ONE barrier; wave DPP pair-reduce; cross-wave combine via
// per-wave LDS slot write + 16-slot DPP re-reduce (no serialized atomics);
// winner index broadcast via v_readlane -> scalar centroid load.
// -----------------------------------------------------------------------------
__global__ __launch_bounds__(NTHREADS, 4) void fps_kernel(
    const float* __restrict__ xyz, int* __restrict__ sorted_idx)
{
    __shared__ unsigned s_bitmap[NPTS / 32];        // 512 words = 2 KiB
    __shared__ unsigned long long s_wkey[2][16];    // parity-buffered wave keys
    __shared__ int s_wt[NTHREADS / 64];             // tail scan totals

    const int tid  = threadIdx.x;
    const int lane = tid & 63;
    const int wid  = tid >> 6;
    const int b    = blockIdx.x;

    if (tid < NPTS / 32) s_bitmap[tid] = 0u;

    const float* xb = xyz + (size_t)b * NPTS * 3;

    // load this thread's PPT contiguous points into registers, then PIN them
    float px[PPT], py[PPT], pz[PPT], pd[PPT];
    {
        const float* p = xb + (size_t)tid * PPT * 3;
        #pragma unroll
        for (int k = 0; k < PPT; ++k) {
            px[k] = p[3 * k + 0];
            py[k] = p[3 * k + 1];
            pz[k] = p[3 * k + 2];
            pd[k] = 1e10f;   // BIG, matches reference init
        }
    }
    #pragma unroll
    for (int k = 0; k < PPT; ++k) {
        // opaque def: compiler can no longer re-load these from memory
        asm volatile("" : "+v"(px[k]), "+v"(py[k]), "+v"(pz[k]));
    }

    // initial farthest = index 0
    float cx = xb[0], cy = xb[1], cz = xb[2];
    if (tid == 0) s_bitmap[0] = 1u;
    __syncthreads();

    for (int s = 0; s < NSAMP - 1; ++s) {
        // --- phase A: exact distance update + inline per-thread argmax ---
        float bv = -1.0f;
        int   bk = 0;
        #pragma unroll
        for (int k = 0; k < PPT; ++k) {
            float dx = __fsub_rn(px[k], cx);
            float dy = __fsub_rn(py[k], cy);
            float dz = __fsub_rn(pz[k], cz);
            float d  = __fadd_rn(__fadd_rn(__fmul_rn(dx, dx), __fmul_rn(dy, dy)),
                                 __fmul_rn(dz, dz));
            float nd = fminf(pd[k], d);
            pd[k] = nd;
            if (nd > bv) { bv = nd; bk = k; }   // strict > keeps smallest k
        }

        // --- wave-level DPP pair-reduce of the packed key (result in lane 63) ---
        unsigned hi = __float_as_uint(bv);
        unsigned lo = ~(unsigned)(tid * PPT + bk);
        red_step<0x111, 0xF>(hi, lo);   // row_shr:1
        red_step<0x112, 0xF>(hi, lo);   // row_shr:2
        red_step<0x114, 0xF>(hi, lo);   // row_shr:4
        red_step<0x118, 0xF>(hi, lo);   // row_shr:8
        red_step<0x142, 0xA>(hi, lo);   // row_bcast:15 (rows 1,3)
        red_step<0x143, 0xC>(hi, lo);   // row_bcast:31 (rows 2,3)

        if (lane == 63)
            s_wkey[s & 1][wid] = ((unsigned long long)hi << 32) | (unsigned long long)lo;

        __syncthreads();   // the ONLY barrier per iteration

        // --- cross-wave combine: every thread reduces the 16 wave keys ---
        unsigned long long k16 = s_wkey[s & 1][lane & 15];
        unsigned rhi = (unsigned)(k16 >> 32);
        unsigned rlo = (unsigned)k16;
        red_step<0x111, 0xF>(rhi, rlo);   // row_shr:1
        red_step<0x112, 0xF>(rhi, rlo);   // row_shr:2
        red_step<0x114, 0xF>(rhi, rlo);   // row_shr:4
        red_step<0x118, 0xF>(rhi, rlo);   // row_shr:8  -> lane 63 has global key
        int g = ~__builtin_amdgcn_readlane((int)rlo, 63);  // uniform winner index

        cx = xb[3 * g + 0];
        cy = xb[3 * g + 1];
        cz = xb[3 * g + 2];

        if (tid == 0) s_bitmap[g >> 5] |= (1u << (g & 31));
    }
    __syncthreads();

    // --- tail: bitmap -> ascending index list via block prefix scan ---
    const int nwords = NPTS / 32;   // 512
    unsigned word = (tid < nwords) ? s_bitmap[tid] : 0u;
    int cnt = __popc(word);
    int inc = cnt;
    #pragma unroll
    for (int off = 1; off < 64; off <<= 1) {
        int n = __shfl_up(inc, off);
        if (lane >= off) inc += n;
    }
    if (lane == 63) s_wt[wid] = inc;
    __syncthreads();
    int base = inc - cnt;
    for (int w = 0; w < wid; ++w) base += s_wt[w];
    int* sb = sorted_idx + (size_t)b * NSAMP;
    int pos = base;
    unsigned wmask = word;
    while (wmask) {
        int k = __ffs(wmask) - 1;
        wmask &= wmask - 1;
        sb[pos++] = tid * 32 + k;
    }
}

// -----------------------------------------------------------------------------
// Gather kernel: one wave per sampled row.
//   out0 = new_xyz [B,S,3]; out1 = concat(xyz, points) [B,S,1,131]; out2 [B,S,128]
// -----------------------------------------------------------------------------
__global__ void gather_kernel(
    const float* __restrict__ xyz, const float* __restrict__ points,
    const float* __restrict__ pres, const int* __restrict__ sorted_idx,
    float* __restrict__ out0, float* __restrict__ out1, float* __restrict__ out2)
{
    int gw   = (int)((blockIdx.x * (unsigned)blockDim.x + threadIdx.x) >> 6);
    int lane = threadIdx.x & 63;
    if (gw >= BATCH * NSAMP) return;
    int b = gw >> 12;               // NSAMP == 4096
    int i = sorted_idx[gw];

    const float* xs = xyz    + ((size_t)b * NPTS + i) * 3;
    const float* ps = points + ((size_t)b * NPTS + i) * 128;
    const float* rs = pres   + ((size_t)b * NPTS + i) * 128;

    if (lane < 3) out0[(size_t)gw * 3 + lane] = xs[lane];

    float* o1 = out1 + (size_t)gw * 131;
    #pragma unroll
    for (int j = 0; j < 3; ++j) {
        int c = lane + 64 * j;
        if (c < 131) o1[c] = (c < 3) ? xs[c] : ps[c - 3];
    }

    const float2* r2 = (const float2*)rs;
    float2* o2 = (float2*)(out2 + (size_t)gw * 128);
    o2[lane] = r2[lane];
}

extern "C" void kernel_launch(void* const* d_in, const int* in_sizes, int n_in,
                              void* d_out, int out_size, void* d_ws, size_t ws_size,
                              hipStream_t stream)
{
    const float* xyz    = (const float*)d_in[0];
    const float* points = (const float*)d_in[1];
    const float* pres   = (const float*)d_in[2];

    float* out  = (float*)d_out;
    float* out0 = out;                                     // B*S*3
    float* out1 = out0 + (size_t)BATCH * NSAMP * 3;        // B*S*131
    float* out2 = out1 + (size_t)BATCH * NSAMP * 131;      // B*S*128

    int* sorted = (int*)d_ws;   // B*S ints = 256 KiB scratch

    fps_kernel<<<BATCH, NTHREADS, 0, stream>>>(xyz, sorted);

    int total_threads = BATCH * NSAMP * 64;   // one wave per sampled row
    int threads = 256;
    int blocks  = total_threads / threads;
    gather_kernel<<<blocks, threads, 0, stream>>>(xyz, points, pres, sorted,
                                                  out0, out1, out2);
}

// Round 5
// 6407.229 us; speedup vs baseline: 1.1834x; 1.1834x over previous
//
#include <hip/hip_runtime.h>

// Problem constants (from setup_inputs: B=16, N=16384, D=128, S=N/4)
#define BATCH    16
#define NPTS     16384
#define NSAMP    4096
#define NTHREADS 1024
#define PPT      16      // NPTS / NTHREADS, points per thread (contiguous)

// DPP move helper (disabled lanes keep old value = own value)
template<int CTRL, int RM>
__device__ __forceinline__ float dpp_movf(float v) {
    return __int_as_float(__builtin_amdgcn_update_dpp(
        __float_as_int(v), __float_as_int(v), CTRL, RM, 0xF, false));
}

// Re-assert arch-VGPR residency of 8 floats (empty asm, zero instructions).
#define PIN8(a, i) asm volatile("" : "+v"(a[(i)+0]), "+v"(a[(i)+1]), "+v"(a[(i)+2]), \
    "+v"(a[(i)+3]), "+v"(a[(i)+4]), "+v"(a[(i)+5]), "+v"(a[(i)+6]), "+v"(a[(i)+7]))

// -----------------------------------------------------------------------------
// FPS kernel: one block per batch, 1024 threads, 16 points/thread.
// Coordinates pinned into arch VGPRs EVERY iteration (a one-time pin let the
// allocator shuttle them through AGPRs: round-4 VGPR_Count=48 + accvgpr traffic).
// Exact reference semantics: dist = min(dist, (x-cx)^2+(y-cy)^2+(z-cz)^2)
// (fp32, no FMA, (xx+yy)+zz association), argmax with first-index tie-break.
// Reductions are value-only DPP max + ballot/ffs index recovery:
//   lane order == index order, wave order == chunk order, so first-set-bit
//   reproduces numpy argmax's first-index tie-break exactly.
// -----------------------------------------------------------------------------
__global__ __launch_bounds__(NTHREADS, 4) void fps_kernel(
    const float* __restrict__ xyz, int* __restrict__ sorted_idx)
{
    __shared__ unsigned s_bitmap[NPTS / 32];        // 512 words = 2 KiB
    __shared__ unsigned long long s_slot[2][16];    // parity-buffered {val,idx} per wave
    __shared__ int s_wt[NTHREADS / 64];             // tail scan totals

    const int tid  = threadIdx.x;
    const int lane = tid & 63;
    const int wid  = tid >> 6;
    const int b    = blockIdx.x;

    if (tid < NPTS / 32) s_bitmap[tid] = 0u;

    const float* xb = xyz + (size_t)b * NPTS * 3;

    // load this thread's PPT contiguous points into registers
    float px[PPT], py[PPT], pz[PPT], pd[PPT];
    {
        const float* p = xb + (size_t)tid * PPT * 3;
        #pragma unroll
        for (int k = 0; k < PPT; ++k) {
            px[k] = p[3 * k + 0];
            py[k] = p[3 * k + 1];
            pz[k] = p[3 * k + 2];
            pd[k] = 1e10f;   // BIG, matches reference init
        }
    }

    // initial farthest = index 0
    float cx = xb[0], cy = xb[1], cz = xb[2];
    if (tid == 0) s_bitmap[0] = 1u;
    __syncthreads();

    for (int s = 0; s < NSAMP - 1; ++s) {
        // pin coords in arch VGPRs at every iteration (0 instructions)
        PIN8(px, 0); PIN8(px, 8);
        PIN8(py, 0); PIN8(py, 8);
        PIN8(pz, 0); PIN8(pz, 8);

        // --- phase A: exact distance update + per-thread argmax ---
        float bv = -1.0f;
        int   bk = 0;
        #pragma unroll
        for (int k = 0; k < PPT; ++k) {
            float dx = __fsub_rn(px[k], cx);
            float dy = __fsub_rn(py[k], cy);
            float dz = __fsub_rn(pz[k], cz);
            float d  = __fadd_rn(__fadd_rn(__fmul_rn(dx, dx), __fmul_rn(dy, dy)),
                                 __fmul_rn(dz, dz));
            float nd = fminf(pd[k], d);
            pd[k] = nd;
            if (nd > bv) { bv = nd; bk = k; }   // strict > keeps smallest k
        }

        // --- phase B: wave max (value-only DPP), then index via ballot ---
        float wv = bv;
        wv = fmaxf(wv, dpp_movf<0x111, 0xF>(wv));   // row_shr:1
        wv = fmaxf(wv, dpp_movf<0x112, 0xF>(wv));   // row_shr:2
        wv = fmaxf(wv, dpp_movf<0x114, 0xF>(wv));   // row_shr:4
        wv = fmaxf(wv, dpp_movf<0x118, 0xF>(wv));   // row_shr:8
        wv = fmaxf(wv, dpp_movf<0x142, 0xA>(wv));   // row_bcast:15
        wv = fmaxf(wv, dpp_movf<0x143, 0xC>(wv));   // row_bcast:31 -> lane 63
        int   m_bits = __builtin_amdgcn_readlane(__float_as_int(wv), 63);
        float m_w    = __int_as_float(m_bits);
        unsigned long long mk = __ballot(bv == m_w);
        int sl   = __ffsll(mk) - 1;                               // smallest lane
        int widx = __builtin_amdgcn_readlane(tid * PPT + bk, sl); // its global index
        if (lane == 0)
            s_slot[s & 1][wid] =
                ((unsigned long long)(unsigned)m_bits << 32) | (unsigned)widx;

        __syncthreads();   // the ONLY barrier per iteration

        // --- phase C: reduce the 16 wave slots (every wave redundantly) ---
        unsigned long long key = s_slot[s & 1][lane & 15];
        float cv = __int_as_float((int)(key >> 32));
        int   ci = (int)(unsigned)key;
        float rv = cv;
        rv = fmaxf(rv, dpp_movf<0x111, 0xF>(rv));
        rv = fmaxf(rv, dpp_movf<0x112, 0xF>(rv));
        rv = fmaxf(rv, dpp_movf<0x114, 0xF>(rv));
        rv = fmaxf(rv, dpp_movf<0x118, 0xF>(rv));   // lane 15 = global max
        int   gm_bits = __builtin_amdgcn_readlane(__float_as_int(rv), 15);
        float gm      = __int_as_float(gm_bits);
        unsigned long long m2 = __ballot(cv == gm);
        int w = __ffsll(m2) - 1;                    // smallest wave id with max
        int g = __builtin_amdgcn_readlane(ci, w);   // uniform winner index

        cx = xb[3 * g + 0];                         // scalar loads (L2-resident)
        cy = xb[3 * g + 1];
        cz = xb[3 * g + 2];

        if (tid == 0) s_bitmap[g >> 5] |= (1u << (g & 31));
    }
    __syncthreads();

    // --- tail: bitmap -> ascending index list via block prefix scan ---
    const int nwords = NPTS / 32;   // 512
    unsigned word = (tid < nwords) ? s_bitmap[tid] : 0u;
    int cnt = __popc(word);
    int inc = cnt;
    #pragma unroll
    for (int off = 1; off < 64; off <<= 1) {
        int n = __shfl_up(inc, off);
        if (lane >= off) inc += n;
    }
    if (lane == 63) s_wt[wid] = inc;
    __syncthreads();
    int base = inc - cnt;
    for (int w = 0; w < wid; ++w) base += s_wt[w];
    int* sb = sorted_idx + (size_t)b * NSAMP;
    int pos = base;
    unsigned wmask = word;
    while (wmask) {
        int k = __ffs(wmask) - 1;
        wmask &= wmask - 1;
        sb[pos++] = tid * 32 + k;
    }
}

// -----------------------------------------------------------------------------
// Gather kernel: one wave per sampled row.
//   out0 = new_xyz [B,S,3]; out1 = concat(xyz, points) [B,S,1,131]; out2 [B,S,128]
// -----------------------------------------------------------------------------
__global__ void gather_kernel(
    const float* __restrict__ xyz, const float* __restrict__ points,
    const float* __restrict__ pres, const int* __restrict__ sorted_idx,
    float* __restrict__ out0, float* __restrict__ out1, float* __restrict__ out2)
{
    int gw   = (int)((blockIdx.x * (unsigned)blockDim.x + threadIdx.x) >> 6);
    int lane = threadIdx.x & 63;
    if (gw >= BATCH * NSAMP) return;
    int b = gw >> 12;               // NSAMP == 4096
    int i = sorted_idx[gw];

    const float* xs = xyz    + ((size_t)b * NPTS + i) * 3;
    const float* ps = points + ((size_t)b * NPTS + i) * 128;
    const float* rs = pres   + ((size_t)b * NPTS + i) * 128;

    if (lane < 3) out0[(size_t)gw * 3 + lane] = xs[lane];

    float* o1 = out1 + (size_t)gw * 131;
    #pragma unroll
    for (int j = 0; j < 3; ++j) {
        int c = lane + 64 * j;
        if (c < 131) o1[c] = (c < 3) ? xs[c] : ps[c - 3];
    }

    const float2* r2 = (const float2*)rs;
    float2* o2 = (float2*)(out2 + (size_t)gw * 128);
    o2[lane] = r2[lane];
}

extern "C" void kernel_launch(void* const* d_in, const int* in_sizes, int n_in,
                              void* d_out, int out_size, void* d_ws, size_t ws_size,
                              hipStream_t stream)
{
    const float* xyz    = (const float*)d_in[0];
    const float* points = (const float*)d_in[1];
    const float* pres   = (const float*)d_in[2];

    float* out  = (float*)d_out;
    float* out0 = out;                                     // B*S*3
    float* out1 = out0 + (size_t)BATCH * NSAMP * 3;        // B*S*131
    float* out2 = out1 + (size_t)BATCH * NSAMP * 131;      // B*S*128

    int* sorted = (int*)d_ws;   // B*S ints = 256 KiB scratch

    fps_kernel<<<BATCH, NTHREADS, 0, stream>>>(xyz, sorted);

    int total_threads = BATCH * NSAMP * 64;   // one wave per sampled row
    int threads = 256;
    int blocks  = total_threads / threads;
    gather_kernel<<<blocks, threads, 0, stream>>>(xyz, points, pres, sorted,
                                                  out0, out1, out2);
}